// Round 13
// baseline (123.856 us; speedup 1.0000x reference)
//
#include <hip/hip_runtime.h>

#define NK 1024
#define DD 48              // 4*4*3 floats per code / per block
#define NL (512 * 512)     // 262144 blocks
#define NTILE 32           // 32 code-tiles of 32 codes

// workspace layout (float offsets)
#define WS_CNH 0           // -0.5*cnorm[k]
#define WS_BFRAG 1024
#define NFRAG_TIDS (32 * 3 * 64)   // bprep threads: tiles * ksteps * lanes

typedef __attribute__((ext_vector_type(8)))  _Float16 half8;
typedef __attribute__((ext_vector_type(16))) float    f32x16;

// fp16 2-split: x = h + m*2^-12, m stored scaled by 4096 (fp16-normal range).
__device__ __forceinline__ void split2(float x, _Float16& h, _Float16& m) {
    h = (_Float16)x;
    const float r = x - (float)h;          // exact
    m = (_Float16)(r * 4096.0f);           // exact scale; RN to fp16
}

// cnh[k] = -0.5 * sum_j cb[k][j]^2 (fp32 sequential FMA; *0.5 exact)
__global__ void vq_cnorm_kernel(const float* __restrict__ cb, float* __restrict__ cnh) {
    int k = blockIdx.x * blockDim.x + threadIdx.x;
    if (k >= NK) return;
    const float* row = cb + k * DD;
    float s = 0.0f;
#pragma unroll
    for (int j = 0; j < DD; ++j) s = fmaf(row[j], row[j], s);
    cnh[k] = -0.5f * s;
}

// B prep: tile-major fragment layout. For tile t:
//   frag[(t*6 + s)*64 + lane]     = h-level, kstep s
//   frag[(t*6 + 3 + s)*64 + lane] = m'-level, kstep s
// code = t*32 + (lane&31), j = s*16 + (lane>>5)*8 + e.
__global__ void vq_bprep_kernel(const float* __restrict__ cb, float* __restrict__ ws) {
    int tid = blockIdx.x * blockDim.x + threadIdx.x;
    if (tid >= NFRAG_TIDS) return;
    int lane = tid & 63;
    int s    = (tid >> 6) % 3;
    int t    = tid / (3 * 64);
    int col = lane & 31, lh = lane >> 5;
    const float* src = cb + (t * 32 + col) * DD + s * 16 + lh * 8;
    half8 vh, vm;
#pragma unroll
    for (int e = 0; e < 8; ++e) {
        _Float16 h, m;
        split2(src[e], h, m);
        vh[e] = h; vm[e] = m;
    }
    half8* base = (half8*)(ws + WS_BFRAG);
    base[(t * 6 + s) * 64 + lane]     = vh;
    base[(t * 6 + 3 + s) * 64 + lane] = vm;
}

#define MFMA16 __builtin_amdgcn_mfma_f32_32x32x16_f16

// Load tile T's 6 B-fragments + cn into the named ping-pong buffer BUF.
#define LOADB(BUF, T) do {                                              \
        const half8* pt_ = bp + (T) * 384;                              \
        BUF##h0 = pt_[0];   BUF##h1 = pt_[64];  BUF##h2 = pt_[128];     \
        BUF##m0 = pt_[192]; BUF##m1 = pt_[256]; BUF##m2 = pt_[320];     \
        BUF##cn = cnp[(T) * 32];                                        \
    } while (0)

// 9 MFMAs in 3 round-robin chains (dep distance 3 = ~97 cy), merge, select.
#define COMPUTE(BUF, T) do {                                            \
        f32x16 c1, c2a, c2b;                                            \
        _Pragma("unroll")                                               \
        for (int q = 0; q < 16; ++q) { c1[q] = BUF##cn; c2a[q] = 0.0f; c2b[q] = 0.0f; } \
        c1  = MFMA16(Ah[0], BUF##h0, c1,  0, 0, 0);                     \
        c2a = MFMA16(Ah[0], BUF##m0, c2a, 0, 0, 0);                     \
        c2b = MFMA16(Am[0], BUF##h0, c2b, 0, 0, 0);                     \
        c1  = MFMA16(Ah[1], BUF##h1, c1,  0, 0, 0);                     \
        c2a = MFMA16(Ah[1], BUF##m1, c2a, 0, 0, 0);                     \
        c2b = MFMA16(Am[1], BUF##h1, c2b, 0, 0, 0);                     \
        c1  = MFMA16(Ah[2], BUF##h2, c1,  0, 0, 0);                     \
        c2a = MFMA16(Ah[2], BUF##m2, c2a, 0, 0, 0);                     \
        c2b = MFMA16(Am[2], BUF##h2, c2b, 0, 0, 0);                     \
        const f32x16 m = (c2a + c2b) * 0x1p-12f + c1;                   \
        const int kl_ = (T) * 32 + col;                                 \
        _Pragma("unroll")                                               \
        for (int q = 0; q < 16; ++q) if (m[q] > best[q]) bk[q] = kl_;   \
        _Pragma("unroll")                                               \
        for (int q = 0; q < 16; ++q) best[q] = fmaxf(best[q], m[q]);    \
    } while (0)

// Main: wave = 32 blocks (one 32x32 tile) x all 1024 codes.
// fp32 GEMM emulated by 3 fp16 products (hh, hm', m'h); c1 init -cn/2.
// argmin(d2) == argmax(m = dot - cn/2), strict-> keeps first occurrence.
__global__ __launch_bounds__(256, 3) void vq_mfma_kernel(const float* __restrict__ img,
                                                         const float* __restrict__ cb,
                                                         const float* __restrict__ ws,
                                                         float* __restrict__ out) {
    __shared__ int lds_bk[4 * 32];
    const int lane  = threadIdx.x & 63;
    const int wid   = threadIdx.x >> 6;
    const int wave  = blockIdx.x * 4 + wid;
    const int wbase = wave * 32;
    const int col = lane & 31, lh = lane >> 5;
    const float* cnp  = ws + WS_CNH + col;              // -cn/2 stream
    const half8* bp   = (const half8*)(ws + WS_BFRAG) + lane;

    // ---- load + split this wave's 32 image blocks into A-fragments ----
    half8 Ah[3], Am[3];
    {
        const int b = wbase + col;
        const int by4 = (b >> 9) * 4, bx = b & 511;
#pragma unroll
        for (int s = 0; s < 3; ++s) {
            const int j0 = s * 16 + lh * 8;
            const int ja = j0, jb = j0 + 4;
            const int ra = (ja * 683) >> 13, ca = ja - 12 * ra;   // j/12, j%12
            const int rb = (jb * 683) >> 13, cb2 = jb - 12 * rb;
            const float4 fa = *(const float4*)(img + ((size_t)(by4 + ra) * 2048 + bx * 4) * 3 + ca);
            const float4 fb = *(const float4*)(img + ((size_t)(by4 + rb) * 2048 + bx * 4) * 3 + cb2);
            const float f[8] = {fa.x, fa.y, fa.z, fa.w, fb.x, fb.y, fb.z, fb.w};
#pragma unroll
            for (int e = 0; e < 8; ++e) {
                _Float16 h, m;
                split2(f[e], h, m);
                Ah[s][e] = h; Am[s][e] = m;
            }
        }
    }

    f32x16 best;
    int bk[16];
#pragma unroll
    for (int q = 0; q < 16; ++q) { best[q] = -__builtin_inff(); bk[q] = 0; }

    // ---- K loop: 2x unrolled, named ping-pong B buffers (true prefetch) ----
    half8 B0h0, B0h1, B0h2, B0m0, B0m1, B0m2;
    half8 B1h0, B1h1, B1h2, B1m0, B1m1, B1m2;
    float B0cn, B1cn;

    LOADB(B0, 0);
#pragma unroll 1
    for (int t = 0; t < NTILE; t += 2) {
        LOADB(B1, t + 1);                                   // prefetch t+1
        COMPUTE(B0, t);
        LOADB(B0, (t + 2 < NTILE) ? t + 2 : NTILE - 1);     // prefetch t+2
        COMPUTE(B1, t + 1);
    }

    // ---- cross-lane lexicographic (max m, min k) reduce over 32 cols ----
#pragma unroll
    for (int q = 0; q < 16; ++q) {
        float d = best[q]; int K = bk[q];
#pragma unroll
        for (int mm = 1; mm < 32; mm <<= 1) {
            const float od = __shfl_xor(d, mm, 64);
            const int   ok = __shfl_xor(K, mm, 64);
            const bool tk = (od > d) || (od == d && ok < K);
            d = tk ? od : d; K = tk ? ok : K;
        }
        const int row32 = (q & 3) + 8 * (q >> 2) + 4 * lh;   // verified C-row map
        if ((lane & 31) == q) lds_bk[wid * 32 + row32] = K;
    }
    __syncthreads();

    // ---- gather chosen code (fp32 original), scatter to image layout ----
    const int myk = lds_bk[wid * 32 + col];
    const int b = wbase + col;
    const int by4 = (b >> 9) * 4, bx = b & 511;
    const float4* qp = (const float4*)(cb + (size_t)myk * DD);
#pragma unroll
    for (int rr = 0; rr < 2; ++rr) {
        const int r = lh * 2 + rr;
        float4* op = (float4*)(out + ((size_t)(by4 + r) * 2048 + bx * 4) * 3);
        op[0] = qp[r * 3 + 0];
        op[1] = qp[r * 3 + 1];
        op[2] = qp[r * 3 + 2];
    }
}

extern "C" void kernel_launch(void* const* d_in, const int* in_sizes, int n_in,
                              void* d_out, int out_size, void* d_ws, size_t ws_size,
                              hipStream_t stream) {
    const float* img = (const float*)d_in[0];   // (2048, 2048, 3) fp32
    const float* cb  = (const float*)d_in[1];   // (1024, 16, 3) fp32
    float* out = (float*)d_out;                 // (2048, 2048, 3) fp32
    float* ws  = (float*)d_ws;

    vq_cnorm_kernel<<<(NK + 255) / 256, 256, 0, stream>>>(cb, ws + WS_CNH);
    vq_bprep_kernel<<<(NFRAG_TIDS + 255) / 256, 256, 0, stream>>>(cb, ws);
    vq_mfma_kernel<<<NL / 32 / 4, 256, 0, stream>>>(img, cb, ws, out);
}